// Round 7
// baseline (380.685 us; speedup 1.0000x reference)
//
#include <hip/hip_runtime.h>
#include <math.h>

#define CIN 256
#define CB 64
#define COUT 256
#define KNB 27
#define EPS 1e-5f

typedef unsigned short u16;
typedef __attribute__((ext_vector_type(8))) short short8;
typedef __attribute__((ext_vector_type(4))) float f32x4;

__device__ inline short f2bf(float f) {
    union { float f; unsigned u; } v; v.f = f;
    unsigned r = v.u + 0x7fff + ((v.u >> 16) & 1);   // RNE
    return (short)(r >> 16);
}
__device__ inline float bf2f(short s) {
    union { unsigned u; float f; } v; v.u = ((unsigned)(u16)s) << 16;
    return v.f;
}
__device__ inline short8 pack8(float4 x0, float4 x1) {
    short8 r;
    r[0] = f2bf(x0.x); r[1] = f2bf(x0.y); r[2] = f2bf(x0.z); r[3] = f2bf(x0.w);
    r[4] = f2bf(x1.x); r[5] = f2bf(x1.y); r[6] = f2bf(x1.z); r[7] = f2bf(x1.w);
    return r;
}

// ---------------------------------------------------------------------------
// Weight prep: bf16 conversion + transposes
//  w1at[d][k] : [64][256]
//  w3t[k][d][c] : [27][64][64]  (plain transpose, read per-wave from L2)
//  w1bt[d][c] : [256][64]
// ---------------------------------------------------------------------------
__global__ void k_prep(const float* __restrict__ w1a, const float* __restrict__ w3,
                       const float* __restrict__ w1b, u16* __restrict__ w1at,
                       u16* __restrict__ w3t, u16* __restrict__ w1bt)
{
    int i = blockIdx.x * 256 + threadIdx.x;
    if (i < 16384) {
        int k = i >> 6, d = i & 63;
        w1at[d * 256 + k] = (u16)f2bf(w1a[i]);
    } else if (i < 126976) {
        int j = i - 16384;
        int k = j >> 12, c = (j >> 6) & 63, d = j & 63;
        w3t[(size_t)k * 4096 + d * 64 + c] = (u16)f2bf(w3[j]);
    } else if (i < 143360) {
        int j = i - 126976;
        int c = j >> 8, d = j & 255;
        w1bt[d * 64 + c] = (u16)f2bf(w1b[j]);
    }
}

// ---------------------------------------------------------------------------
// GEMM1: t1[N,64](bf16) = data[N,256](f32->bf16) @ w1a ; GN1 stats
// ---------------------------------------------------------------------------
__global__ __launch_bounds__(256) void k_gemm1(const float* __restrict__ data,
        const u16* __restrict__ w1at, u16* __restrict__ t1,
        float* __restrict__ stats, int n)
{
    __shared__ float s_sum[32], s_sq[32];
    const int tid = threadIdx.x;
    if (tid < 32) { s_sum[tid] = 0.f; s_sq[tid] = 0.f; }
    __syncthreads();
    const int l = tid & 63, wv = tid >> 6;
    const int ll = l & 15, lh = l >> 4;
    const int rowbase = blockIdx.x * 256 + wv * 64;

    f32x4 acc[4][4] = {};
#pragma unroll
    for (int kc = 0; kc < 8; ++kc) {
        short8 b[4];
#pragma unroll
        for (int f = 0; f < 4; ++f)
            b[f] = *(const short8*)(w1at + (size_t)(f * 16 + ll) * 256 + kc * 32 + lh * 8);
#pragma unroll
        for (int rt = 0; rt < 4; ++rt) {
            int row = rowbase + rt * 16 + ll;
            int rowc = (row < n) ? row : 0;
            const float* ar = data + (size_t)rowc * CIN + kc * 32 + lh * 8;
            short8 a = pack8(*(const float4*)ar, *(const float4*)(ar + 4));
#pragma unroll
            for (int f = 0; f < 4; ++f)
                acc[rt][f] = __builtin_amdgcn_mfma_f32_16x16x32_bf16(a, b[f], acc[rt][f], 0, 0, 0);
        }
    }
    float gs[4] = {0.f, 0.f, 0.f, 0.f}, gq[4] = {0.f, 0.f, 0.f, 0.f};
#pragma unroll
    for (int rt = 0; rt < 4; ++rt) {
#pragma unroll
        for (int f = 0; f < 4; ++f) {
#pragma unroll
            for (int r = 0; r < 4; ++r) {
                int rr = rowbase + rt * 16 + lh * 4 + r;
                if (rr < n) {
                    float v = acc[rt][f][r];
                    t1[(size_t)rr * CB + f * 16 + ll] = (u16)f2bf(v);
                    gs[f] += v; gq[f] += v * v;
                }
            }
        }
    }
#pragma unroll
    for (int f = 0; f < 4; ++f) {
        float s = gs[f], q = gq[f];
        s += __shfl_xor(s, 1); s += __shfl_xor(s, 16); s += __shfl_xor(s, 32);
        q += __shfl_xor(q, 1); q += __shfl_xor(q, 16); q += __shfl_xor(q, 32);
        if ((l & 0x31) == 0) {
            atomicAdd(&s_sum[f * 8 + (ll >> 1)], s);
            atomicAdd(&s_sq [f * 8 + (ll >> 1)], q);
        }
    }
    __syncthreads();
    if (tid < 32) {
        atomicAdd(&stats[tid], s_sum[tid]);
        atomicAdd(&stats[32 + tid], s_sq[tid]);
    }
}

// ---------------------------------------------------------------------------
// GN apply + ReLU, in-place on a [N,64] bf16 buffer (2 channels per group)
// ---------------------------------------------------------------------------
__global__ void k_apply64(u16* __restrict__ buf, const float* __restrict__ st,
        const float* __restrict__ gamma, const float* __restrict__ beta, int n)
{
    const float cnt = (float)n * 2.0f;
    const int total = n * 8;
    for (int i = blockIdx.x * blockDim.x + threadIdx.x; i < total;
         i += gridDim.x * blockDim.x) {
        int c0 = (i & 7) * 8;
        short8 v = ((short8*)buf)[i];
#pragma unroll
        for (int j = 0; j < 8; ++j) {
            int c = c0 + j, g = c >> 1;
            float mu = st[g] / cnt;
            float var = st[32 + g] / cnt - mu * mu;
            float inv = rsqrtf(var + EPS);
            float x = bf2f(v[j]);
            x = fmaxf((x - mu) * inv * gamma[c] + beta[c], 0.f);
            v[j] = f2bf(x);
        }
        ((short8*)buf)[i] = v;
    }
}

// ---------------------------------------------------------------------------
// Octree conv (bf16 MFMA), BARRIER-FREE: y[n,d] = sum_k x[neigh[n,k],:] w3[k]
// 128 nodes/block, 4 independent waves x 32 rows (acc[2][4], 16 MFMA/k).
// No LDS in the k-loop: B-frags read per-wave from L2-resident w3t (8KB/k),
// 1-deep; gathers 2-deep; neighbor indices loaded 1 step before their use.
// Full unroll -> rotating buffers are SSA-renamed, all indices static.
// ---------------------------------------------------------------------------
__global__ __launch_bounds__(256) void k_conv(const u16* __restrict__ xb,
        const int* __restrict__ neigh, const u16* __restrict__ w3t,
        u16* __restrict__ y, float* __restrict__ stats, int n)
{
    __shared__ float s_sum[32], s_sq[32];
    const int tid = threadIdx.x;
    if (tid < 32) { s_sum[tid] = 0.f; s_sq[tid] = 0.f; }
    const int row0 = blockIdx.x * 128;
    const int l = tid & 63, wv = tid >> 6;
    const int ll = l & 15, lh = l >> 4;
    const int r0 = row0 + wv * 32 + ll;
    const int r1 = r0 + 16;
    const int r0c = (r0 < n) ? r0 : 0;
    const int r1c = (r1 < n) ? r1 : 0;
    const int* __restrict__ nrow0 = neigh + (size_t)r0c * KNB;
    const int* __restrict__ nrow1 = neigh + (size_t)r1c * KNB;
    const u16* __restrict__ bbase = w3t + ll * 64 + lh * 8;

    short8 A[3][4];     // gather bufs (rot %3): [0]=r0 c0-31,[1]=r0 c32-63,[2],[3]=r1
    short8 Bv[2][8];    // B bufs (rot &1): [f]=c0-31 d-tile f, [4+f]=c32-63
    int idxq[2][2];     // idx pipeline (loaded 1 step before gather use)

    // prologue: gather k=0,1; B k=0; idx for k=2
    {
        int i0 = nrow0[0], i1 = nrow1[0], i2 = nrow0[1], i3 = nrow1[1];
        const u16* xa = xb + (size_t)i0 * CB + lh * 8;
        const u16* xc = xb + (size_t)i1 * CB + lh * 8;
        A[0][0] = *(const short8*)xa; A[0][1] = *(const short8*)(xa + 32);
        A[0][2] = *(const short8*)xc; A[0][3] = *(const short8*)(xc + 32);
        const u16* xe = xb + (size_t)i2 * CB + lh * 8;
        const u16* xg = xb + (size_t)i3 * CB + lh * 8;
        A[1][0] = *(const short8*)xe; A[1][1] = *(const short8*)(xe + 32);
        A[1][2] = *(const short8*)xg; A[1][3] = *(const short8*)(xg + 32);
#pragma unroll
        for (int f = 0; f < 4; ++f) {
            Bv[0][f]     = *(const short8*)(bbase + f * 1024);
            Bv[0][4 + f] = *(const short8*)(bbase + f * 1024 + 32);
        }
        idxq[0][0] = nrow0[2]; idxq[0][1] = nrow1[2];
    }

    f32x4 acc[2][4] = {};
#pragma unroll
    for (int k = 0; k < KNB; ++k) {
        if (k + 1 < KNB) {   // B prefetch (1-deep, L2-hot)
            const u16* bp = bbase + (size_t)(k + 1) * 4096;
#pragma unroll
            for (int f = 0; f < 4; ++f) {
                Bv[(k + 1) & 1][f]     = *(const short8*)(bp + f * 1024);
                Bv[(k + 1) & 1][4 + f] = *(const short8*)(bp + f * 1024 + 32);
            }
        }
        if (k + 2 < KNB) {   // gather prefetch (2-deep), idx loaded last step
            int i0 = idxq[k & 1][0], i1 = idxq[k & 1][1];
            const u16* xa = xb + (size_t)i0 * CB + lh * 8;
            const u16* xc = xb + (size_t)i1 * CB + lh * 8;
            A[(k + 2) % 3][0] = *(const short8*)xa;
            A[(k + 2) % 3][1] = *(const short8*)(xa + 32);
            A[(k + 2) % 3][2] = *(const short8*)xc;
            A[(k + 2) % 3][3] = *(const short8*)(xc + 32);
        }
        if (k + 3 < KNB) {   // idx prefetch for next step's gather
            idxq[(k + 1) & 1][0] = nrow0[k + 3];
            idxq[(k + 1) & 1][1] = nrow1[k + 3];
        }
        __builtin_amdgcn_sched_barrier(0);   // pin prefetch issue above MFMA
#pragma unroll
        for (int f = 0; f < 4; ++f) {
            acc[0][f] = __builtin_amdgcn_mfma_f32_16x16x32_bf16(A[k % 3][0], Bv[k & 1][f],     acc[0][f], 0, 0, 0);
            acc[0][f] = __builtin_amdgcn_mfma_f32_16x16x32_bf16(A[k % 3][1], Bv[k & 1][4 + f], acc[0][f], 0, 0, 0);
            acc[1][f] = __builtin_amdgcn_mfma_f32_16x16x32_bf16(A[k % 3][2], Bv[k & 1][f],     acc[1][f], 0, 0, 0);
            acc[1][f] = __builtin_amdgcn_mfma_f32_16x16x32_bf16(A[k % 3][3], Bv[k & 1][4 + f], acc[1][f], 0, 0, 0);
        }
    }

    float gs[4] = {0.f, 0.f, 0.f, 0.f}, gq[4] = {0.f, 0.f, 0.f, 0.f};
#pragma unroll
    for (int rt = 0; rt < 2; ++rt) {
#pragma unroll
        for (int f = 0; f < 4; ++f) {
#pragma unroll
            for (int r = 0; r < 4; ++r) {
                int rr = row0 + wv * 32 + rt * 16 + lh * 4 + r;
                if (rr < n) {
                    float v = acc[rt][f][r];
                    y[(size_t)rr * CB + f * 16 + ll] = (u16)f2bf(v);
                    gs[f] += v; gq[f] += v * v;
                }
            }
        }
    }
#pragma unroll
    for (int f = 0; f < 4; ++f) {
        float s = gs[f], q = gq[f];
        s += __shfl_xor(s, 1); s += __shfl_xor(s, 16); s += __shfl_xor(s, 32);
        q += __shfl_xor(q, 1); q += __shfl_xor(q, 16); q += __shfl_xor(q, 32);
        if ((l & 0x31) == 0) {
            atomicAdd(&s_sum[f * 8 + (ll >> 1)], s);
            atomicAdd(&s_sq [f * 8 + (ll >> 1)], q);
        }
    }
    __syncthreads();
    if (tid < 32) {
        atomicAdd(&stats[64 + tid], s_sum[tid]);
        atomicAdd(&stats[96 + tid], s_sq[tid]);
    }
}

// ---------------------------------------------------------------------------
// GEMM2 with fused GN2-apply on the A path:
// z[N,256] = relu(gn2(y))[N,64](bf16) @ w1b ; GN3 stats.
// Stores bf16 into zb (if non-null) else f32 into z.
// ---------------------------------------------------------------------------
__global__ __launch_bounds__(256) void k_gemm2(const u16* __restrict__ y2,
        const u16* __restrict__ w1bt, float* __restrict__ z, u16* __restrict__ zb,
        float* __restrict__ stats, const float* __restrict__ g3,
        const float* __restrict__ b3, int n)
{
    __shared__ float s_sum[8], s_sq[8];
    const int tid = threadIdx.x;
    if (tid < 8) { s_sum[tid] = 0.f; s_sq[tid] = 0.f; }
    __syncthreads();
    const int l = tid & 63, wv = tid >> 6;
    const int ll = l & 15, lh = l >> 4;
    const int rowbase = blockIdx.x * 256 + wv * 64;
    const int cb = blockIdx.y;

    // per-lane GN2 scale/shift for the 16 k-channels this lane touches
    const float* st2 = stats + 64;
    const float cnt2 = (float)n * 2.0f;
    float sc[16], sh[16];
#pragma unroll
    for (int j = 0; j < 16; ++j) {
        int c = (j < 8) ? (lh * 8 + j) : (32 + lh * 8 + (j - 8));
        int g = c >> 1;
        float mu = st2[g] / cnt2;
        float var = st2[32 + g] / cnt2 - mu * mu;
        float inv = rsqrtf(var + EPS);
        float gm = g3[c];
        sc[j] = inv * gm;
        sh[j] = b3[c] - mu * inv * gm;
    }

    short8 b0[4], b1[4];
#pragma unroll
    for (int f = 0; f < 4; ++f) {
        const u16* br = w1bt + (size_t)(cb * 64 + f * 16 + ll) * CB + lh * 8;
        b0[f] = *(const short8*)(br);
        b1[f] = *(const short8*)(br + 32);
    }
    f32x4 acc[4][4] = {};
#pragma unroll
    for (int rt = 0; rt < 4; ++rt) {
        int row = rowbase + rt * 16 + ll;
        int rowc = (row < n) ? row : 0;
        const u16* ar = y2 + (size_t)rowc * CB + lh * 8;
        short8 r0 = *(const short8*)(ar);
        short8 r1 = *(const short8*)(ar + 32);
        short8 a0, a1;
#pragma unroll
        for (int j = 0; j < 8; ++j) {
            a0[j] = f2bf(fmaxf(bf2f(r0[j]) * sc[j] + sh[j], 0.f));
            a1[j] = f2bf(fmaxf(bf2f(r1[j]) * sc[8 + j] + sh[8 + j], 0.f));
        }
#pragma unroll
        for (int f = 0; f < 4; ++f) {
            acc[rt][f] = __builtin_amdgcn_mfma_f32_16x16x32_bf16(a0, b0[f], acc[rt][f], 0, 0, 0);
            acc[rt][f] = __builtin_amdgcn_mfma_f32_16x16x32_bf16(a1, b1[f], acc[rt][f], 0, 0, 0);
        }
    }
    float gs[4] = {0.f, 0.f, 0.f, 0.f}, gq[4] = {0.f, 0.f, 0.f, 0.f};
#pragma unroll
    for (int rt = 0; rt < 4; ++rt) {
#pragma unroll
        for (int f = 0; f < 4; ++f) {
#pragma unroll
            for (int r = 0; r < 4; ++r) {
                int rr = rowbase + rt * 16 + lh * 4 + r;
                if (rr < n) {
                    float v = acc[rt][f][r];
                    size_t off = (size_t)rr * COUT + cb * 64 + f * 16 + ll;
                    if (zb) zb[off] = (u16)f2bf(v); else z[off] = v;
                    gs[f] += v; gq[f] += v * v;
                }
            }
        }
    }
#pragma unroll
    for (int f = 0; f < 4; ++f) {
        float s = gs[f], q = gq[f];
        s += __shfl_xor(s, 1); s += __shfl_xor(s, 2); s += __shfl_xor(s, 4);
        s += __shfl_xor(s, 16); s += __shfl_xor(s, 32);
        q += __shfl_xor(q, 1); q += __shfl_xor(q, 2); q += __shfl_xor(q, 4);
        q += __shfl_xor(q, 16); q += __shfl_xor(q, 32);
        if ((l & 0x37) == 0) {
            atomicAdd(&s_sum[f * 2 + (ll >> 3)], s);
            atomicAdd(&s_sq [f * 2 + (ll >> 3)], q);
        }
    }
    __syncthreads();
    if (tid < 8) {
        atomicAdd(&stats[128 + cb * 8 + tid], s_sum[tid]);
        atomicAdd(&stats[160 + cb * 8 + tid], s_sq[tid]);
    }
}

// ---------------------------------------------------------------------------
// Final: out = relu(GN3(z) + data). bf16-z variant (z in ws).
// ---------------------------------------------------------------------------
__global__ void k_final_bf(float* __restrict__ out, const u16* __restrict__ zb,
        const float* __restrict__ data, const float* __restrict__ st,
        const float* __restrict__ gamma, const float* __restrict__ beta, int n)
{
    const float cnt = (float)n * 8.0f;
    const int total = n * 32;   // 8-channel chunks
    for (int i = blockIdx.x * blockDim.x + threadIdx.x; i < total;
         i += gridDim.x * blockDim.x) {
        int c0 = (i & 31) * 8;
        int g = c0 >> 3;
        float mu = st[g] / cnt;
        float var = st[32 + g] / cnt - mu * mu;
        float inv = rsqrtf(var + EPS);
        short8 zv = ((const short8*)zb)[i];
        float dd[8], oo[8];
        *(float4*)dd = *(const float4*)(data + (size_t)i * 8);
        *(float4*)(dd + 4) = *(const float4*)(data + (size_t)i * 8 + 4);
#pragma unroll
        for (int j = 0; j < 8; ++j)
            oo[j] = fmaxf((bf2f(zv[j]) - mu) * inv * gamma[c0 + j] + beta[c0 + j] + dd[j], 0.f);
        *(float4*)(out + (size_t)i * 8) = *(float4*)oo;
        *(float4*)(out + (size_t)i * 8 + 4) = *(float4*)(oo + 4);
    }
}

// f32-z fallback (z already in d_out), in-place
__global__ void k_final(float* __restrict__ zo, const float* __restrict__ data,
        const float* __restrict__ st, const float* __restrict__ gamma,
        const float* __restrict__ beta, int n)
{
    const float cnt = (float)n * 8.0f;
    const int total = n * (COUT / 4);
    for (int i = blockIdx.x * blockDim.x + threadIdx.x; i < total;
         i += gridDim.x * blockDim.x) {
        int c4 = (i & (COUT / 4 - 1)) * 4;
        int g = c4 >> 3;
        float mu = st[g] / cnt;
        float var = st[32 + g] / cnt - mu * mu;
        float inv = rsqrtf(var + EPS);
        float4 zv = *(float4*)(zo + (size_t)i * 4);
        float4 dv = *(const float4*)(data + (size_t)i * 4);
        zv.x = fmaxf((zv.x - mu) * inv * gamma[c4 + 0] + beta[c4 + 0] + dv.x, 0.f);
        zv.y = fmaxf((zv.y - mu) * inv * gamma[c4 + 1] + beta[c4 + 1] + dv.y, 0.f);
        zv.z = fmaxf((zv.z - mu) * inv * gamma[c4 + 2] + beta[c4 + 2] + dv.z, 0.f);
        zv.w = fmaxf((zv.w - mu) * inv * gamma[c4 + 3] + beta[c4 + 3] + dv.w, 0.f);
        *(float4*)(zo + (size_t)i * 4) = zv;
    }
}

// ---------------------------------------------------------------------------
extern "C" void kernel_launch(void* const* d_in, const int* in_sizes, int n_in,
                              void* d_out, int out_size, void* d_ws, size_t ws_size,
                              hipStream_t stream)
{
    const float* data = (const float*)d_in[0];
    const int*   neigh = (const int*)d_in[1];
    const float* w1a = (const float*)d_in[2];
    const float* g1a = (const float*)d_in[3];
    const float* b1a = (const float*)d_in[4];
    const float* w3  = (const float*)d_in[5];
    const float* g3  = (const float*)d_in[6];
    const float* b3  = (const float*)d_in[7];
    const float* w1b = (const float*)d_in[8];
    const float* g1b = (const float*)d_in[9];
    const float* b1b = (const float*)d_in[10];
    float* out = (float*)d_out;
    float* ws  = (float*)d_ws;

    const int n = in_sizes[0] / CIN;   // 150000

    // ws layout: stats[192] (pad 256 f32) | w1at | w3t | w1bt | t1 | ybuf | [zb]
    float* stats = ws;
    u16* w1at = (u16*)(ws + 256);
    u16* w3t  = w1at + 16384;
    u16* w1bt = w3t + 110592;
    u16* t1   = w1bt + 16384;
    u16* ybuf = t1 + (size_t)n * CB;
    u16* zb   = nullptr;
    {
        size_t need = 1024 + 286720 + (size_t)n * CB * 4 + (size_t)n * COUT * 2;
        if (ws_size >= need) zb = ybuf + (size_t)n * CB;
    }

    hipMemsetAsync(stats, 0, 192 * sizeof(float), stream);

    const int nb128 = (n + 127) / 128;
    const int nb256 = (n + 255) / 256;
    k_prep<<<560, 256, 0, stream>>>(w1a, w3, w1b, w1at, w3t, w1bt);
    k_gemm1<<<nb256, 256, 0, stream>>>(data, w1at, t1, stats, n);
    k_apply64<<<2048, 256, 0, stream>>>(t1, stats, g1a, b1a, n);
    k_conv<<<nb128, 256, 0, stream>>>(t1, neigh, w3t, ybuf, stats, n);
    k_gemm2<<<dim3(nb256, 4), 256, 0, stream>>>(ybuf, w1bt, out, zb, stats, g3, b3, n);
    if (zb)
        k_final_bf<<<2048, 256, 0, stream>>>(out, zb, data, stats + 128, g1b, b1b, n);
    else
        k_final<<<2048, 256, 0, stream>>>(out, data, stats + 128, g1b, b1b, n);
}

// Round 8
// 290.897 us; speedup vs baseline: 1.3087x; 1.3087x over previous
//
#include <hip/hip_runtime.h>
#include <math.h>

#define CIN 256
#define CB 64
#define COUT 256
#define KNB 27
#define EPS 1e-5f

typedef unsigned short u16;
typedef __attribute__((ext_vector_type(8))) short short8;
typedef __attribute__((ext_vector_type(4))) float f32x4;

typedef const __attribute__((address_space(1))) unsigned int* gas_u32p;
typedef __attribute__((address_space(3))) unsigned int* las_u32p;
// async global->LDS, 16B per lane, dest = wave-uniform base + lane*16
#define GLL(g, p) __builtin_amdgcn_global_load_lds((gas_u32p)(const void*)(g), \
        (las_u32p)(void*)(p), 16, 0, 0)

__device__ inline short f2bf(float f) {
    union { float f; unsigned u; } v; v.f = f;
    unsigned r = v.u + 0x7fff + ((v.u >> 16) & 1);   // RNE
    return (short)(r >> 16);
}
__device__ inline float bf2f(short s) {
    union { unsigned u; float f; } v; v.u = ((unsigned)(u16)s) << 16;
    return v.f;
}
__device__ inline short8 pack8(float4 x0, float4 x1) {
    short8 r;
    r[0] = f2bf(x0.x); r[1] = f2bf(x0.y); r[2] = f2bf(x0.z); r[3] = f2bf(x0.w);
    r[4] = f2bf(x1.x); r[5] = f2bf(x1.y); r[6] = f2bf(x1.z); r[7] = f2bf(x1.w);
    return r;
}

// ---------------------------------------------------------------------------
// Weight prep: bf16 conversion + transposes (+ XOR-swizzled w3 LDS image)
//  w1at[d][k] : [64][256]
//  w3img[k]   : per k an 8KB image, ushort index d*64 + (c ^ ((d&7)<<3))
//  w1bt[d][c] : [256][64]
// ---------------------------------------------------------------------------
__global__ void k_prep(const float* __restrict__ w1a, const float* __restrict__ w3,
                       const float* __restrict__ w1b, u16* __restrict__ w1at,
                       u16* __restrict__ w3img, u16* __restrict__ w1bt)
{
    int i = blockIdx.x * 256 + threadIdx.x;
    if (i < 16384) {
        int k = i >> 6, d = i & 63;
        w1at[d * 256 + k] = (u16)f2bf(w1a[i]);
    } else if (i < 126976) {
        int j = i - 16384;
        int k = j >> 12, c = (j >> 6) & 63, d = j & 63;
        w3img[(size_t)k * 4096 + d * 64 + (c ^ ((d & 7) << 3))] = (u16)f2bf(w3[j]);
    } else if (i < 143360) {
        int j = i - 126976;
        int c = j >> 8, d = j & 255;
        w1bt[d * 64 + c] = (u16)f2bf(w1b[j]);
    }
}

// ---------------------------------------------------------------------------
// GEMM1: t1[N,64](bf16) = data[N,256](f32->bf16) @ w1a ; GN1 stats
// ---------------------------------------------------------------------------
__global__ __launch_bounds__(256) void k_gemm1(const float* __restrict__ data,
        const u16* __restrict__ w1at, u16* __restrict__ t1,
        float* __restrict__ stats, int n)
{
    __shared__ float s_sum[32], s_sq[32];
    const int tid = threadIdx.x;
    if (tid < 32) { s_sum[tid] = 0.f; s_sq[tid] = 0.f; }
    __syncthreads();
    const int l = tid & 63, wv = tid >> 6;
    const int ll = l & 15, lh = l >> 4;
    const int rowbase = blockIdx.x * 256 + wv * 64;

    f32x4 acc[4][4] = {};
#pragma unroll
    for (int kc = 0; kc < 8; ++kc) {
        short8 b[4];
#pragma unroll
        for (int f = 0; f < 4; ++f)
            b[f] = *(const short8*)(w1at + (size_t)(f * 16 + ll) * 256 + kc * 32 + lh * 8);
#pragma unroll
        for (int rt = 0; rt < 4; ++rt) {
            int row = rowbase + rt * 16 + ll;
            int rowc = (row < n) ? row : 0;
            const float* ar = data + (size_t)rowc * CIN + kc * 32 + lh * 8;
            short8 a = pack8(*(const float4*)ar, *(const float4*)(ar + 4));
#pragma unroll
            for (int f = 0; f < 4; ++f)
                acc[rt][f] = __builtin_amdgcn_mfma_f32_16x16x32_bf16(a, b[f], acc[rt][f], 0, 0, 0);
        }
    }
    float gs[4] = {0.f, 0.f, 0.f, 0.f}, gq[4] = {0.f, 0.f, 0.f, 0.f};
#pragma unroll
    for (int rt = 0; rt < 4; ++rt) {
#pragma unroll
        for (int f = 0; f < 4; ++f) {
#pragma unroll
            for (int r = 0; r < 4; ++r) {
                int rr = rowbase + rt * 16 + lh * 4 + r;
                if (rr < n) {
                    float v = acc[rt][f][r];
                    t1[(size_t)rr * CB + f * 16 + ll] = (u16)f2bf(v);
                    gs[f] += v; gq[f] += v * v;
                }
            }
        }
    }
#pragma unroll
    for (int f = 0; f < 4; ++f) {
        float s = gs[f], q = gq[f];
        s += __shfl_xor(s, 1); s += __shfl_xor(s, 16); s += __shfl_xor(s, 32);
        q += __shfl_xor(q, 1); q += __shfl_xor(q, 16); q += __shfl_xor(q, 32);
        if ((l & 0x31) == 0) {
            atomicAdd(&s_sum[f * 8 + (ll >> 1)], s);
            atomicAdd(&s_sq [f * 8 + (ll >> 1)], q);
        }
    }
    __syncthreads();
    if (tid < 32) {
        atomicAdd(&stats[tid], s_sum[tid]);
        atomicAdd(&stats[32 + tid], s_sq[tid]);
    }
}

// ---------------------------------------------------------------------------
// GN apply + ReLU, in-place on a [N,64] bf16 buffer (2 channels per group)
// ---------------------------------------------------------------------------
__global__ void k_apply64(u16* __restrict__ buf, const float* __restrict__ st,
        const float* __restrict__ gamma, const float* __restrict__ beta, int n)
{
    const float cnt = (float)n * 2.0f;
    const int total = n * 8;
    for (int i = blockIdx.x * blockDim.x + threadIdx.x; i < total;
         i += gridDim.x * blockDim.x) {
        int c0 = (i & 7) * 8;
        short8 v = ((short8*)buf)[i];
#pragma unroll
        for (int j = 0; j < 8; ++j) {
            int c = c0 + j, g = c >> 1;
            float mu = st[g] / cnt;
            float var = st[32 + g] / cnt - mu * mu;
            float inv = rsqrtf(var + EPS);
            float x = bf2f(v[j]);
            x = fmaxf((x - mu) * inv * gamma[c] + beta[c], 0.f);
            v[j] = f2bf(x);
        }
        ((short8*)buf)[i] = v;
    }
}

// ---------------------------------------------------------------------------
// Octree conv (bf16 MFMA): y[n,d] = sum_k sum_c x[neigh[n,k],c] * w3[k,c,d]
// 128 nodes x 64 d per block, 4 waves (each 32 rows, acc[2][4], 16 MFMA/k).
// r6 structure (GLL dbuf staging of swizzled w3) with COUNTED-vmcnt barriers:
// per k, issue order is [GLL(k+1) x2, gathers A(k+1) x4, idx(k+3) x2];
// before s_barrier wait only vmcnt(6) (GLL retired in-order, gathers+idx fly
// across the barrier) + lgkmcnt(0) (ds_reads retired before buffer reuse).
// ---------------------------------------------------------------------------
__global__ __launch_bounds__(256) void k_conv(const u16* __restrict__ xb,
        const int* __restrict__ neigh, const u16* __restrict__ w3img,
        u16* __restrict__ y, float* __restrict__ stats, int n)
{
    __shared__ u16 s_w3[2][4096];     // 2 x 8 KB swizzled [64d][64c] images
    __shared__ float s_sum[32], s_sq[32];
    const int tid = threadIdx.x;
    if (tid < 32) { s_sum[tid] = 0.f; s_sq[tid] = 0.f; }
    const int row0 = blockIdx.x * 128;
    const int l = tid & 63, wv = tid >> 6;
    const int ll = l & 15, lh = l >> 4;
    const int r0 = row0 + wv * 32 + ll;
    const int r1 = r0 + 16;
    const int r0c = (r0 < n) ? r0 : 0;
    const int r1c = (r1 < n) ? r1 : 0;
    const int* __restrict__ nrow0 = neigh + (size_t)r0c * KNB;
    const int* __restrict__ nrow1 = neigh + (size_t)r1c * KNB;

    // per-lane staging addresses: wave wv covers bytes [wv*2048, wv*2048+2048)
    u16* ld0 = &s_w3[0][0] + wv * 1024 + l * 8;
    u16* ld1 = &s_w3[1][0] + wv * 1024 + l * 8;
    const u16* gw = w3img + wv * 1024 + l * 8;

    // prologue: GLL first (so counted waits can retire it), then idx, gathers
    GLL(gw, ld0);
    GLL(gw + 512, ld0 + 512);
    int ia0 = nrow0[0], ib0 = nrow1[0];
    int ian = nrow0[1], ibn = nrow1[1];
    short8 a0c, a1c, a2c, a3c;
    {
        const u16* xa = xb + (size_t)ia0 * CB + lh * 8;
        const u16* xc = xb + (size_t)ib0 * CB + lh * 8;
        a0c = *(const short8*)xa; a1c = *(const short8*)(xa + 32);
        a2c = *(const short8*)xc; a3c = *(const short8*)(xc + 32);
    }
    // allow idx(4) + gathers(4) outstanding; GLL (first 2, in-order) retired
    asm volatile("s_waitcnt vmcnt(8) lgkmcnt(0)" ::: "memory");
    __builtin_amdgcn_s_barrier();
    __builtin_amdgcn_sched_barrier(0);

    f32x4 acc[2][4] = {};
#pragma unroll
    for (int k = 0; k < KNB; ++k) {
        const int cur = k & 1;
        short8 a0n, a1n, a2n, a3n;
        int iaf = 0, ibf = 0;
        if (k + 1 < KNB) {
            // 1) GLL w3[k+1] into other buffer (must be first vmem this step)
            const u16* gsrc = w3img + (size_t)(k + 1) * 4096 + wv * 1024 + l * 8;
            u16* ldst = cur ? ld0 : ld1;
            GLL(gsrc, ldst);
            GLL(gsrc + 512, ldst + 512);
            // 2) gather A(k+1); addresses from idx regs loaded last step
            const u16* xa = xb + (size_t)ian * CB + lh * 8;
            const u16* xc = xb + (size_t)ibn * CB + lh * 8;
            a0n = *(const short8*)xa; a1n = *(const short8*)(xa + 32);
            a2n = *(const short8*)xc; a3n = *(const short8*)(xc + 32);
        }
        // 3) idx prefetch for next step's gathers
        if (k + 2 < KNB) { iaf = nrow0[k + 2]; ibf = nrow1[k + 2]; }
        __builtin_amdgcn_sched_barrier(0);   // pin prefetch issue above MFMA
        // compute tile k: B frags from LDS, shared across both row tiles
#pragma unroll
        for (int f = 0; f < 4; ++f) {
            int d = f * 16 + ll;
            int swz = (d & 7) << 4;
            short8 b0 = *(const short8*)((const char*)&s_w3[cur][0] + d * 128 + ((lh * 16) ^ swz));
            short8 b1 = *(const short8*)((const char*)&s_w3[cur][0] + d * 128 + ((64 + lh * 16) ^ swz));
            acc[0][f] = __builtin_amdgcn_mfma_f32_16x16x32_bf16(a0c, b0, acc[0][f], 0, 0, 0);
            acc[0][f] = __builtin_amdgcn_mfma_f32_16x16x32_bf16(a1c, b1, acc[0][f], 0, 0, 0);
            acc[1][f] = __builtin_amdgcn_mfma_f32_16x16x32_bf16(a2c, b0, acc[1][f], 0, 0, 0);
            acc[1][f] = __builtin_amdgcn_mfma_f32_16x16x32_bf16(a3c, b1, acc[1][f], 0, 0, 0);
        }
        if (k + 1 < KNB) {
            a0c = a0n; a1c = a1n; a2c = a2n; a3c = a3n;
            ian = iaf; ibn = ibf;
            // counted drain: retire this step's GLLs only; gathers (+idx) may
            // stay in flight across the barrier. lgkmcnt(0): ds_reads retired
            // before any wave overwrites this buffer next step.
            if (k + 2 < KNB)
                asm volatile("s_waitcnt vmcnt(6) lgkmcnt(0)" ::: "memory");
            else
                asm volatile("s_waitcnt vmcnt(4) lgkmcnt(0)" ::: "memory");
            __builtin_amdgcn_s_barrier();
            __builtin_amdgcn_sched_barrier(0);
        }
    }

    float gs[4] = {0.f, 0.f, 0.f, 0.f}, gq[4] = {0.f, 0.f, 0.f, 0.f};
#pragma unroll
    for (int rt = 0; rt < 2; ++rt) {
#pragma unroll
        for (int f = 0; f < 4; ++f) {
#pragma unroll
            for (int r = 0; r < 4; ++r) {
                int rr = row0 + wv * 32 + rt * 16 + lh * 4 + r;
                if (rr < n) {
                    float v = acc[rt][f][r];
                    y[(size_t)rr * CB + f * 16 + ll] = (u16)f2bf(v);
                    gs[f] += v; gq[f] += v * v;
                }
            }
        }
    }
#pragma unroll
    for (int f = 0; f < 4; ++f) {
        float s = gs[f], q = gq[f];
        s += __shfl_xor(s, 1); s += __shfl_xor(s, 16); s += __shfl_xor(s, 32);
        q += __shfl_xor(q, 1); q += __shfl_xor(q, 16); q += __shfl_xor(q, 32);
        if ((l & 0x31) == 0) {
            atomicAdd(&s_sum[f * 8 + (ll >> 1)], s);
            atomicAdd(&s_sq [f * 8 + (ll >> 1)], q);
        }
    }
    __syncthreads();
    if (tid < 32) {
        atomicAdd(&stats[64 + tid], s_sum[tid]);
        atomicAdd(&stats[96 + tid], s_sq[tid]);
    }
}

// ---------------------------------------------------------------------------
// GEMM2 with fused GN2-apply on the A path:
// z[N,256] = relu(gn2(y))[N,64](bf16) @ w1b ; GN3 stats.
// Stores bf16 into zb (if non-null) else f32 into z.
// ---------------------------------------------------------------------------
__global__ __launch_bounds__(256) void k_gemm2(const u16* __restrict__ y2,
        const u16* __restrict__ w1bt, float* __restrict__ z, u16* __restrict__ zb,
        float* __restrict__ stats, const float* __restrict__ g3,
        const float* __restrict__ b3, int n)
{
    __shared__ float s_sum[8], s_sq[8];
    const int tid = threadIdx.x;
    if (tid < 8) { s_sum[tid] = 0.f; s_sq[tid] = 0.f; }
    __syncthreads();
    const int l = tid & 63, wv = tid >> 6;
    const int ll = l & 15, lh = l >> 4;
    const int rowbase = blockIdx.x * 256 + wv * 64;
    const int cb = blockIdx.y;

    // per-lane GN2 scale/shift for the 16 k-channels this lane touches
    const float* st2 = stats + 64;
    const float cnt2 = (float)n * 2.0f;
    float sc[16], sh[16];
#pragma unroll
    for (int j = 0; j < 16; ++j) {
        int c = (j < 8) ? (lh * 8 + j) : (32 + lh * 8 + (j - 8));
        int g = c >> 1;
        float mu = st2[g] / cnt2;
        float var = st2[32 + g] / cnt2 - mu * mu;
        float inv = rsqrtf(var + EPS);
        float gm = g3[c];
        sc[j] = inv * gm;
        sh[j] = b3[c] - mu * inv * gm;
    }

    short8 b0[4], b1[4];
#pragma unroll
    for (int f = 0; f < 4; ++f) {
        const u16* br = w1bt + (size_t)(cb * 64 + f * 16 + ll) * CB + lh * 8;
        b0[f] = *(const short8*)(br);
        b1[f] = *(const short8*)(br + 32);
    }
    f32x4 acc[4][4] = {};
#pragma unroll
    for (int rt = 0; rt < 4; ++rt) {
        int row = rowbase + rt * 16 + ll;
        int rowc = (row < n) ? row : 0;
        const u16* ar = y2 + (size_t)rowc * CB + lh * 8;
        short8 r0 = *(const short8*)(ar);
        short8 r1 = *(const short8*)(ar + 32);
        short8 a0, a1;
#pragma unroll
        for (int j = 0; j < 8; ++j) {
            a0[j] = f2bf(fmaxf(bf2f(r0[j]) * sc[j] + sh[j], 0.f));
            a1[j] = f2bf(fmaxf(bf2f(r1[j]) * sc[8 + j] + sh[8 + j], 0.f));
        }
#pragma unroll
        for (int f = 0; f < 4; ++f) {
            acc[rt][f] = __builtin_amdgcn_mfma_f32_16x16x32_bf16(a0, b0[f], acc[rt][f], 0, 0, 0);
            acc[rt][f] = __builtin_amdgcn_mfma_f32_16x16x32_bf16(a1, b1[f], acc[rt][f], 0, 0, 0);
        }
    }
    float gs[4] = {0.f, 0.f, 0.f, 0.f}, gq[4] = {0.f, 0.f, 0.f, 0.f};
#pragma unroll
    for (int rt = 0; rt < 4; ++rt) {
#pragma unroll
        for (int f = 0; f < 4; ++f) {
#pragma unroll
            for (int r = 0; r < 4; ++r) {
                int rr = rowbase + rt * 16 + lh * 4 + r;
                if (rr < n) {
                    float v = acc[rt][f][r];
                    size_t off = (size_t)rr * COUT + cb * 64 + f * 16 + ll;
                    if (zb) zb[off] = (u16)f2bf(v); else z[off] = v;
                    gs[f] += v; gq[f] += v * v;
                }
            }
        }
    }
#pragma unroll
    for (int f = 0; f < 4; ++f) {
        float s = gs[f], q = gq[f];
        s += __shfl_xor(s, 1); s += __shfl_xor(s, 2); s += __shfl_xor(s, 4);
        s += __shfl_xor(s, 16); s += __shfl_xor(s, 32);
        q += __shfl_xor(q, 1); q += __shfl_xor(q, 2); q += __shfl_xor(q, 4);
        q += __shfl_xor(q, 16); q += __shfl_xor(q, 32);
        if ((l & 0x37) == 0) {
            atomicAdd(&s_sum[f * 2 + (ll >> 3)], s);
            atomicAdd(&s_sq [f * 2 + (ll >> 3)], q);
        }
    }
    __syncthreads();
    if (tid < 8) {
        atomicAdd(&stats[128 + cb * 8 + tid], s_sum[tid]);
        atomicAdd(&stats[160 + cb * 8 + tid], s_sq[tid]);
    }
}

// ---------------------------------------------------------------------------
// Final: out = relu(GN3(z) + data). bf16-z variant (z in ws).
// ---------------------------------------------------------------------------
__global__ void k_final_bf(float* __restrict__ out, const u16* __restrict__ zb,
        const float* __restrict__ data, const float* __restrict__ st,
        const float* __restrict__ gamma, const float* __restrict__ beta, int n)
{
    const float cnt = (float)n * 8.0f;
    const int total = n * 32;   // 8-channel chunks
    for (int i = blockIdx.x * blockDim.x + threadIdx.x; i < total;
         i += gridDim.x * blockDim.x) {
        int c0 = (i & 31) * 8;
        int g = c0 >> 3;
        float mu = st[g] / cnt;
        float var = st[32 + g] / cnt - mu * mu;
        float inv = rsqrtf(var + EPS);
        short8 zv = ((const short8*)zb)[i];
        float dd[8], oo[8];
        *(float4*)dd = *(const float4*)(data + (size_t)i * 8);
        *(float4*)(dd + 4) = *(const float4*)(data + (size_t)i * 8 + 4);
#pragma unroll
        for (int j = 0; j < 8; ++j)
            oo[j] = fmaxf((bf2f(zv[j]) - mu) * inv * gamma[c0 + j] + beta[c0 + j] + dd[j], 0.f);
        *(float4*)(out + (size_t)i * 8) = *(float4*)oo;
        *(float4*)(out + (size_t)i * 8 + 4) = *(float4*)(oo + 4);
    }
}

// f32-z fallback (z already in d_out), in-place
__global__ void k_final(float* __restrict__ zo, const float* __restrict__ data,
        const float* __restrict__ st, const float* __restrict__ gamma,
        const float* __restrict__ beta, int n)
{
    const float cnt = (float)n * 8.0f;
    const int total = n * (COUT / 4);
    for (int i = blockIdx.x * blockDim.x + threadIdx.x; i < total;
         i += gridDim.x * blockDim.x) {
        int c4 = (i & (COUT / 4 - 1)) * 4;
        int g = c4 >> 3;
        float mu = st[g] / cnt;
        float var = st[32 + g] / cnt - mu * mu;
        float inv = rsqrtf(var + EPS);
        float4 zv = *(float4*)(zo + (size_t)i * 4);
        float4 dv = *(const float4*)(data + (size_t)i * 4);
        zv.x = fmaxf((zv.x - mu) * inv * gamma[c4 + 0] + beta[c4 + 0] + dv.x, 0.f);
        zv.y = fmaxf((zv.y - mu) * inv * gamma[c4 + 1] + beta[c4 + 1] + dv.y, 0.f);
        zv.z = fmaxf((zv.z - mu) * inv * gamma[c4 + 2] + beta[c4 + 2] + dv.z, 0.f);
        zv.w = fmaxf((zv.w - mu) * inv * gamma[c4 + 3] + beta[c4 + 3] + dv.w, 0.f);
        *(float4*)(zo + (size_t)i * 4) = zv;
    }
}

// ---------------------------------------------------------------------------
extern "C" void kernel_launch(void* const* d_in, const int* in_sizes, int n_in,
                              void* d_out, int out_size, void* d_ws, size_t ws_size,
                              hipStream_t stream)
{
    const float* data = (const float*)d_in[0];
    const int*   neigh = (const int*)d_in[1];
    const float* w1a = (const float*)d_in[2];
    const float* g1a = (const float*)d_in[3];
    const float* b1a = (const float*)d_in[4];
    const float* w3  = (const float*)d_in[5];
    const float* g3  = (const float*)d_in[6];
    const float* b3  = (const float*)d_in[7];
    const float* w1b = (const float*)d_in[8];
    const float* g1b = (const float*)d_in[9];
    const float* b1b = (const float*)d_in[10];
    float* out = (float*)d_out;
    float* ws  = (float*)d_ws;

    const int n = in_sizes[0] / CIN;   // 150000

    // ws layout: stats[192] (pad 256 f32) | w1at | w3img | w1bt | t1 | ybuf | [zb]
    float* stats = ws;
    u16* w1at  = (u16*)(ws + 256);
    u16* w3img = w1at + 16384;
    u16* w1bt  = w3img + 110592;
    u16* t1    = w1bt + 16384;
    u16* ybuf  = t1 + (size_t)n * CB;
    u16* zb    = nullptr;
    {
        size_t need = 1024 + 286720 + (size_t)n * CB * 4 + (size_t)n * COUT * 2;
        if (ws_size >= need) zb = ybuf + (size_t)n * CB;
    }

    hipMemsetAsync(stats, 0, 192 * sizeof(float), stream);

    const int nb128 = (n + 127) / 128;
    const int nb256 = (n + 255) / 256;
    k_prep<<<560, 256, 0, stream>>>(w1a, w3, w1b, w1at, w3img, w1bt);
    k_gemm1<<<nb256, 256, 0, stream>>>(data, w1at, t1, stats, n);
    k_apply64<<<2048, 256, 0, stream>>>(t1, stats, g1a, b1a, n);
    k_conv<<<nb128, 256, 0, stream>>>(t1, neigh, w3img, ybuf, stats, n);
    k_gemm2<<<dim3(nb256, 4), 256, 0, stream>>>(ybuf, w1bt, out, zb, stats, g3, b3, n);
    if (zb)
        k_final_bf<<<2048, 256, 0, stream>>>(out, zb, data, stats + 128, g1b, b1b, n);
    else
        k_final<<<2048, 256, 0, stream>>>(out, data, stats + 128, g1b, b1b, n);
}

// Round 9
// 284.922 us; speedup vs baseline: 1.3361x; 1.0210x over previous
//
#include <hip/hip_runtime.h>
#include <math.h>

#define CIN 256
#define CB 64
#define COUT 256
#define KNB 27
#define EPS 1e-5f

typedef unsigned short u16;
typedef __attribute__((ext_vector_type(8))) short short8;
typedef __attribute__((ext_vector_type(4))) float f32x4;

typedef const __attribute__((address_space(1))) unsigned int* gas_u32p;
typedef __attribute__((address_space(3))) unsigned int* las_u32p;
// async global->LDS, 16B per lane, dest = wave-uniform base + lane*16
#define GLL(g, p) __builtin_amdgcn_global_load_lds((gas_u32p)(const void*)(g), \
        (las_u32p)(void*)(p), 16, 0, 0)

__device__ inline short f2bf(float f) {
    union { float f; unsigned u; } v; v.f = f;
    unsigned r = v.u + 0x7fff + ((v.u >> 16) & 1);   // RNE
    return (short)(r >> 16);
}
__device__ inline float bf2f(short s) {
    union { unsigned u; float f; } v; v.u = ((unsigned)(u16)s) << 16;
    return v.f;
}
__device__ inline short8 pack8(float4 x0, float4 x1) {
    short8 r;
    r[0] = f2bf(x0.x); r[1] = f2bf(x0.y); r[2] = f2bf(x0.z); r[3] = f2bf(x0.w);
    r[4] = f2bf(x1.x); r[5] = f2bf(x1.y); r[6] = f2bf(x1.z); r[7] = f2bf(x1.w);
    return r;
}

// ---------------------------------------------------------------------------
// Weight prep: bf16 conversion + transposes (+ XOR-swizzled w3 LDS image)
//  w1at[d][k] : [64][256]
//  w3img[k]   : per k an 8KB image, ushort index d*64 + (c ^ ((d&7)<<3))
//  w1bt[d][c] : [256][64]
// ---------------------------------------------------------------------------
__global__ void k_prep(const float* __restrict__ w1a, const float* __restrict__ w3,
                       const float* __restrict__ w1b, u16* __restrict__ w1at,
                       u16* __restrict__ w3img, u16* __restrict__ w1bt)
{
    int i = blockIdx.x * 256 + threadIdx.x;
    if (i < 16384) {
        int k = i >> 6, d = i & 63;
        w1at[d * 256 + k] = (u16)f2bf(w1a[i]);
    } else if (i < 126976) {
        int j = i - 16384;
        int k = j >> 12, c = (j >> 6) & 63, d = j & 63;
        w3img[(size_t)k * 4096 + d * 64 + (c ^ ((d & 7) << 3))] = (u16)f2bf(w3[j]);
    } else if (i < 143360) {
        int j = i - 126976;
        int c = j >> 8, d = j & 255;
        w1bt[d * 64 + c] = (u16)f2bf(w1b[j]);
    }
}

// ---------------------------------------------------------------------------
// GEMM1: t1[N,64](bf16) = data[N,256](f32->bf16) @ w1a ; GN1 stats
// ---------------------------------------------------------------------------
__global__ __launch_bounds__(256) void k_gemm1(const float* __restrict__ data,
        const u16* __restrict__ w1at, u16* __restrict__ t1,
        float* __restrict__ stats, int n)
{
    __shared__ float s_sum[32], s_sq[32];
    const int tid = threadIdx.x;
    if (tid < 32) { s_sum[tid] = 0.f; s_sq[tid] = 0.f; }
    __syncthreads();
    const int l = tid & 63, wv = tid >> 6;
    const int ll = l & 15, lh = l >> 4;
    const int rowbase = blockIdx.x * 256 + wv * 64;

    f32x4 acc[4][4] = {};
#pragma unroll
    for (int kc = 0; kc < 8; ++kc) {
        short8 b[4];
#pragma unroll
        for (int f = 0; f < 4; ++f)
            b[f] = *(const short8*)(w1at + (size_t)(f * 16 + ll) * 256 + kc * 32 + lh * 8);
#pragma unroll
        for (int rt = 0; rt < 4; ++rt) {
            int row = rowbase + rt * 16 + ll;
            int rowc = (row < n) ? row : 0;
            const float* ar = data + (size_t)rowc * CIN + kc * 32 + lh * 8;
            short8 a = pack8(*(const float4*)ar, *(const float4*)(ar + 4));
#pragma unroll
            for (int f = 0; f < 4; ++f)
                acc[rt][f] = __builtin_amdgcn_mfma_f32_16x16x32_bf16(a, b[f], acc[rt][f], 0, 0, 0);
        }
    }
    float gs[4] = {0.f, 0.f, 0.f, 0.f}, gq[4] = {0.f, 0.f, 0.f, 0.f};
#pragma unroll
    for (int rt = 0; rt < 4; ++rt) {
#pragma unroll
        for (int f = 0; f < 4; ++f) {
#pragma unroll
            for (int r = 0; r < 4; ++r) {
                int rr = rowbase + rt * 16 + lh * 4 + r;
                if (rr < n) {
                    float v = acc[rt][f][r];
                    t1[(size_t)rr * CB + f * 16 + ll] = (u16)f2bf(v);
                    gs[f] += v; gq[f] += v * v;
                }
            }
        }
    }
#pragma unroll
    for (int f = 0; f < 4; ++f) {
        float s = gs[f], q = gq[f];
        s += __shfl_xor(s, 1); s += __shfl_xor(s, 16); s += __shfl_xor(s, 32);
        q += __shfl_xor(q, 1); q += __shfl_xor(q, 16); q += __shfl_xor(q, 32);
        if ((l & 0x31) == 0) {
            atomicAdd(&s_sum[f * 8 + (ll >> 1)], s);
            atomicAdd(&s_sq [f * 8 + (ll >> 1)], q);
        }
    }
    __syncthreads();
    if (tid < 32) {
        atomicAdd(&stats[tid], s_sum[tid]);
        atomicAdd(&stats[32 + tid], s_sq[tid]);
    }
}

// ---------------------------------------------------------------------------
// GN apply + ReLU, in-place on a [N,64] bf16 buffer (2 channels per group)
// ---------------------------------------------------------------------------
__global__ void k_apply64(u16* __restrict__ buf, const float* __restrict__ st,
        const float* __restrict__ gamma, const float* __restrict__ beta, int n)
{
    const float cnt = (float)n * 2.0f;
    const int total = n * 8;
    for (int i = blockIdx.x * blockDim.x + threadIdx.x; i < total;
         i += gridDim.x * blockDim.x) {
        int c0 = (i & 7) * 8;
        short8 v = ((short8*)buf)[i];
#pragma unroll
        for (int j = 0; j < 8; ++j) {
            int c = c0 + j, g = c >> 1;
            float mu = st[g] / cnt;
            float var = st[32 + g] / cnt - mu * mu;
            float inv = rsqrtf(var + EPS);
            float x = bf2f(v[j]);
            x = fmaxf((x - mu) * inv * gamma[c] + beta[c], 0.f);
            v[j] = f2bf(x);
        }
        ((short8*)buf)[i] = v;
    }
}

// ---------------------------------------------------------------------------
// Octree conv (bf16 MFMA): y[n,d] = sum_k sum_c x[neigh[n,k],c] * w3[k,c,d]
// 128 nodes x 64 d per block, 4 waves (each 32 rows, acc[2][4], 16 MFMA/k).
// CHUNKED staging: w3 staged 3 k's at a time (24KB), double-buffered (48KB
// LDS). GLLs for chunk c+1 issued at START of chunk c (3 steps to land).
// Only 1 barrier per chunk (9 total), counted vmcnt(12) retires exactly the
// 6 GLLs (in-order) while gathers/idx stay in flight. Per step, issue order
// is idx(k+4) -> gathers(k+2) -> compute(k): every consume only forces ops
// >=2 steps old (landed) -> true 2-deep gather pipeline.
// ---------------------------------------------------------------------------
__global__ __launch_bounds__(256) void k_conv(const u16* __restrict__ xb,
        const int* __restrict__ neigh, const u16* __restrict__ w3img,
        u16* __restrict__ y, float* __restrict__ stats, int n)
{
    __shared__ u16 s_w3[2][12288];    // 2 x 24KB (3 swizzled 8KB k-pages each)
    __shared__ float s_sum[32], s_sq[32];
    const int tid = threadIdx.x;
    if (tid < 32) { s_sum[tid] = 0.f; s_sq[tid] = 0.f; }
    const int row0 = blockIdx.x * 128;
    const int l = tid & 63, wv = tid >> 6;
    const int ll = l & 15, lh = l >> 4;
    const int r0 = row0 + wv * 32 + ll;
    const int r1 = r0 + 16;
    const int* __restrict__ nrow0 = neigh + (size_t)((r0 < n) ? r0 : 0) * KNB;
    const int* __restrict__ nrow1 = neigh + (size_t)((r1 < n) ? r1 : 0) * KNB;
    const int so = wv * 3072 + l * 8;   // ushort staging offset (6KB/wave)

    short8 A[3][4];     // gather register generations, slot k%3
    int ixa[3], ixb[3]; // idx generations, slot k%3

    // ---- prologue: idx(0,1) -> GLL(chunk0) -> gathers(0,1) -> idx(2,3) ----
    ixa[0] = nrow0[0]; ixb[0] = nrow1[0];
    ixa[1] = nrow0[1]; ixb[1] = nrow1[1];
    __builtin_amdgcn_sched_barrier(0);
#pragma unroll
    for (int j = 0; j < 6; ++j)
        GLL(w3img + so + j * 512, &s_w3[0][0] + so + j * 512);
    __builtin_amdgcn_sched_barrier(0);
    {
        const u16* xa = xb + (size_t)ixa[0] * CB + lh * 8;
        const u16* xc = xb + (size_t)ixb[0] * CB + lh * 8;
        A[0][0] = *(const short8*)xa; A[0][1] = *(const short8*)(xa + 32);
        A[0][2] = *(const short8*)xc; A[0][3] = *(const short8*)(xc + 32);
    }
    {
        const u16* xa = xb + (size_t)ixa[1] * CB + lh * 8;
        const u16* xc = xb + (size_t)ixb[1] * CB + lh * 8;
        A[1][0] = *(const short8*)xa; A[1][1] = *(const short8*)(xa + 32);
        A[1][2] = *(const short8*)xc; A[1][3] = *(const short8*)(xc + 32);
    }
    ixa[2] = nrow0[2]; ixb[2] = nrow1[2];
    ixa[0] = nrow0[3]; ixb[0] = nrow1[3];      // idx(3) -> slot 0 (idx0 dead)
    // retire the 6 GLLs (oldest beyond the 12 young gather/idx ops)
    asm volatile("s_waitcnt vmcnt(12) lgkmcnt(0)" ::: "memory");
    __builtin_amdgcn_s_barrier();
    __builtin_amdgcn_sched_barrier(0);

    f32x4 acc[2][4] = {};
#pragma unroll
    for (int c = 0; c < 9; ++c) {
        const int buf = c & 1;
        if (c < 8) {   // stage chunk c+1 into other buffer (lands in ~3 steps)
            const u16* gsrc = w3img + (size_t)(c + 1) * 12288 + so;
            u16* ldst = &s_w3[buf ^ 1][0] + so;
#pragma unroll
            for (int j = 0; j < 6; ++j)
                GLL(gsrc + j * 512, ldst + j * 512);
        }
        __builtin_amdgcn_sched_barrier(0);
#pragma unroll
        for (int s = 0; s < 3; ++s) {
            const int k = c * 3 + s;
            // 1) idx prefetch (2 steps ahead of its gather)
            if (k + 4 <= 26) {
                ixa[(k + 4) % 3] = nrow0[k + 4];
                ixb[(k + 4) % 3] = nrow1[k + 4];
            }
            __builtin_amdgcn_sched_barrier(0);
            // 2) gather prefetch (2 steps ahead of its MFMA)
            if (k + 2 <= 26) {
                const u16* xa = xb + (size_t)ixa[(k + 2) % 3] * CB + lh * 8;
                const u16* xc = xb + (size_t)ixb[(k + 2) % 3] * CB + lh * 8;
                A[(k + 2) % 3][0] = *(const short8*)xa;
                A[(k + 2) % 3][1] = *(const short8*)(xa + 32);
                A[(k + 2) % 3][2] = *(const short8*)xc;
                A[(k + 2) % 3][3] = *(const short8*)(xc + 32);
            }
            __builtin_amdgcn_sched_barrier(0);
            // 3) compute step k from LDS page s of buffer buf
            const char* bpage = (const char*)&s_w3[buf][0] + s * 8192;
#pragma unroll
            for (int f = 0; f < 4; ++f) {
                int d = f * 16 + ll;
                int swz = (d & 7) << 4;
                short8 b0 = *(const short8*)(bpage + d * 128 + ((lh * 16) ^ swz));
                short8 b1 = *(const short8*)(bpage + d * 128 + ((64 + lh * 16) ^ swz));
                acc[0][f] = __builtin_amdgcn_mfma_f32_16x16x32_bf16(A[k % 3][0], b0, acc[0][f], 0, 0, 0);
                acc[0][f] = __builtin_amdgcn_mfma_f32_16x16x32_bf16(A[k % 3][1], b1, acc[0][f], 0, 0, 0);
                acc[1][f] = __builtin_amdgcn_mfma_f32_16x16x32_bf16(A[k % 3][2], b0, acc[1][f], 0, 0, 0);
                acc[1][f] = __builtin_amdgcn_mfma_f32_16x16x32_bf16(A[k % 3][3], b1, acc[1][f], 0, 0, 0);
            }
        }
        // counted barrier: retire chunk c+1's GLLs; keep young gathers/idx
        // in flight (outstanding younger-than-GLL: c<=6 -> 12, c==7 -> 10)
        if (c < 7)
            asm volatile("s_waitcnt vmcnt(12) lgkmcnt(0)" ::: "memory");
        else if (c == 7)
            asm volatile("s_waitcnt vmcnt(10) lgkmcnt(0)" ::: "memory");
        if (c < 8) {
            __builtin_amdgcn_s_barrier();
            __builtin_amdgcn_sched_barrier(0);
        }
    }

    float gs[4] = {0.f, 0.f, 0.f, 0.f}, gq[4] = {0.f, 0.f, 0.f, 0.f};
#pragma unroll
    for (int rt = 0; rt < 2; ++rt) {
#pragma unroll
        for (int f = 0; f < 4; ++f) {
#pragma unroll
            for (int r = 0; r < 4; ++r) {
                int rr = row0 + wv * 32 + rt * 16 + lh * 4 + r;
                if (rr < n) {
                    float v = acc[rt][f][r];
                    y[(size_t)rr * CB + f * 16 + ll] = (u16)f2bf(v);
                    gs[f] += v; gq[f] += v * v;
                }
            }
        }
    }
#pragma unroll
    for (int f = 0; f < 4; ++f) {
        float s = gs[f], q = gq[f];
        s += __shfl_xor(s, 1); s += __shfl_xor(s, 16); s += __shfl_xor(s, 32);
        q += __shfl_xor(q, 1); q += __shfl_xor(q, 16); q += __shfl_xor(q, 32);
        if ((l & 0x31) == 0) {
            atomicAdd(&s_sum[f * 8 + (ll >> 1)], s);
            atomicAdd(&s_sq [f * 8 + (ll >> 1)], q);
        }
    }
    __syncthreads();
    if (tid < 32) {
        atomicAdd(&stats[64 + tid], s_sum[tid]);
        atomicAdd(&stats[96 + tid], s_sq[tid]);
    }
}

// ---------------------------------------------------------------------------
// GEMM2 with fused GN2-apply on the A path:
// z[N,256] = relu(gn2(y))[N,64](bf16) @ w1b ; GN3 stats.
// Stores bf16 into zb (if non-null) else f32 into z.
// ---------------------------------------------------------------------------
__global__ __launch_bounds__(256) void k_gemm2(const u16* __restrict__ y2,
        const u16* __restrict__ w1bt, float* __restrict__ z, u16* __restrict__ zb,
        float* __restrict__ stats, const float* __restrict__ g3,
        const float* __restrict__ b3, int n)
{
    __shared__ float s_sum[8], s_sq[8];
    const int tid = threadIdx.x;
    if (tid < 8) { s_sum[tid] = 0.f; s_sq[tid] = 0.f; }
    __syncthreads();
    const int l = tid & 63, wv = tid >> 6;
    const int ll = l & 15, lh = l >> 4;
    const int rowbase = blockIdx.x * 256 + wv * 64;
    const int cb = blockIdx.y;

    // per-lane GN2 scale/shift for the 16 k-channels this lane touches
    const float* st2 = stats + 64;
    const float cnt2 = (float)n * 2.0f;
    float sc[16], sh[16];
#pragma unroll
    for (int j = 0; j < 16; ++j) {
        int c = (j < 8) ? (lh * 8 + j) : (32 + lh * 8 + (j - 8));
        int g = c >> 1;
        float mu = st2[g] / cnt2;
        float var = st2[32 + g] / cnt2 - mu * mu;
        float inv = rsqrtf(var + EPS);
        float gm = g3[c];
        sc[j] = inv * gm;
        sh[j] = b3[c] - mu * inv * gm;
    }

    short8 b0[4], b1[4];
#pragma unroll
    for (int f = 0; f < 4; ++f) {
        const u16* br = w1bt + (size_t)(cb * 64 + f * 16 + ll) * CB + lh * 8;
        b0[f] = *(const short8*)(br);
        b1[f] = *(const short8*)(br + 32);
    }
    f32x4 acc[4][4] = {};
#pragma unroll
    for (int rt = 0; rt < 4; ++rt) {
        int row = rowbase + rt * 16 + ll;
        int rowc = (row < n) ? row : 0;
        const u16* ar = y2 + (size_t)rowc * CB + lh * 8;
        short8 r0 = *(const short8*)(ar);
        short8 r1 = *(const short8*)(ar + 32);
        short8 a0, a1;
#pragma unroll
        for (int j = 0; j < 8; ++j) {
            a0[j] = f2bf(fmaxf(bf2f(r0[j]) * sc[j] + sh[j], 0.f));
            a1[j] = f2bf(fmaxf(bf2f(r1[j]) * sc[8 + j] + sh[8 + j], 0.f));
        }
#pragma unroll
        for (int f = 0; f < 4; ++f) {
            acc[rt][f] = __builtin_amdgcn_mfma_f32_16x16x32_bf16(a0, b0[f], acc[rt][f], 0, 0, 0);
            acc[rt][f] = __builtin_amdgcn_mfma_f32_16x16x32_bf16(a1, b1[f], acc[rt][f], 0, 0, 0);
        }
    }
    float gs[4] = {0.f, 0.f, 0.f, 0.f}, gq[4] = {0.f, 0.f, 0.f, 0.f};
#pragma unroll
    for (int rt = 0; rt < 4; ++rt) {
#pragma unroll
        for (int f = 0; f < 4; ++f) {
#pragma unroll
            for (int r = 0; r < 4; ++r) {
                int rr = rowbase + rt * 16 + lh * 4 + r;
                if (rr < n) {
                    float v = acc[rt][f][r];
                    size_t off = (size_t)rr * COUT + cb * 64 + f * 16 + ll;
                    if (zb) zb[off] = (u16)f2bf(v); else z[off] = v;
                    gs[f] += v; gq[f] += v * v;
                }
            }
        }
    }
#pragma unroll
    for (int f = 0; f < 4; ++f) {
        float s = gs[f], q = gq[f];
        s += __shfl_xor(s, 1); s += __shfl_xor(s, 2); s += __shfl_xor(s, 4);
        s += __shfl_xor(s, 16); s += __shfl_xor(s, 32);
        q += __shfl_xor(q, 1); q += __shfl_xor(q, 2); q += __shfl_xor(q, 4);
        q += __shfl_xor(q, 16); q += __shfl_xor(q, 32);
        if ((l & 0x37) == 0) {
            atomicAdd(&s_sum[f * 2 + (ll >> 3)], s);
            atomicAdd(&s_sq [f * 2 + (ll >> 3)], q);
        }
    }
    __syncthreads();
    if (tid < 8) {
        atomicAdd(&stats[128 + cb * 8 + tid], s_sum[tid]);
        atomicAdd(&stats[160 + cb * 8 + tid], s_sq[tid]);
    }
}

// ---------------------------------------------------------------------------
// Final: out = relu(GN3(z) + data). bf16-z variant (z in ws).
// ---------------------------------------------------------------------------
__global__ void k_final_bf(float* __restrict__ out, const u16* __restrict__ zb,
        const float* __restrict__ data, const float* __restrict__ st,
        const float* __restrict__ gamma, const float* __restrict__ beta, int n)
{
    const float cnt = (float)n * 8.0f;
    const int total = n * 32;   // 8-channel chunks
    for (int i = blockIdx.x * blockDim.x + threadIdx.x; i < total;
         i += gridDim.x * blockDim.x) {
        int c0 = (i & 31) * 8;
        int g = c0 >> 3;
        float mu = st[g] / cnt;
        float var = st[32 + g] / cnt - mu * mu;
        float inv = rsqrtf(var + EPS);
        short8 zv = ((const short8*)zb)[i];
        float dd[8], oo[8];
        *(float4*)dd = *(const float4*)(data + (size_t)i * 8);
        *(float4*)(dd + 4) = *(const float4*)(data + (size_t)i * 8 + 4);
#pragma unroll
        for (int j = 0; j < 8; ++j)
            oo[j] = fmaxf((bf2f(zv[j]) - mu) * inv * gamma[c0 + j] + beta[c0 + j] + dd[j], 0.f);
        *(float4*)(out + (size_t)i * 8) = *(float4*)oo;
        *(float4*)(out + (size_t)i * 8 + 4) = *(float4*)(oo + 4);
    }
}

// f32-z fallback (z already in d_out), in-place
__global__ void k_final(float* __restrict__ zo, const float* __restrict__ data,
        const float* __restrict__ st, const float* __restrict__ gamma,
        const float* __restrict__ beta, int n)
{
    const float cnt = (float)n * 8.0f;
    const int total = n * (COUT / 4);
    for (int i = blockIdx.x * blockDim.x + threadIdx.x; i < total;
         i += gridDim.x * blockDim.x) {
        int c4 = (i & (COUT / 4 - 1)) * 4;
        int g = c4 >> 3;
        float mu = st[g] / cnt;
        float var = st[32 + g] / cnt - mu * mu;
        float inv = rsqrtf(var + EPS);
        float4 zv = *(float4*)(zo + (size_t)i * 4);
        float4 dv = *(const float4*)(data + (size_t)i * 4);
        zv.x = fmaxf((zv.x - mu) * inv * gamma[c4 + 0] + beta[c4 + 0] + dv.x, 0.f);
        zv.y = fmaxf((zv.y - mu) * inv * gamma[c4 + 1] + beta[c4 + 1] + dv.y, 0.f);
        zv.z = fmaxf((zv.z - mu) * inv * gamma[c4 + 2] + beta[c4 + 2] + dv.z, 0.f);
        zv.w = fmaxf((zv.w - mu) * inv * gamma[c4 + 3] + beta[c4 + 3] + dv.w, 0.f);
        *(float4*)(zo + (size_t)i * 4) = zv;
    }
}

// ---------------------------------------------------------------------------
extern "C" void kernel_launch(void* const* d_in, const int* in_sizes, int n_in,
                              void* d_out, int out_size, void* d_ws, size_t ws_size,
                              hipStream_t stream)
{
    const float* data = (const float*)d_in[0];
    const int*   neigh = (const int*)d_in[1];
    const float* w1a = (const float*)d_in[2];
    const float* g1a = (const float*)d_in[3];
    const float* b1a = (const float*)d_in[4];
    const float* w3  = (const float*)d_in[5];
    const float* g3  = (const float*)d_in[6];
    const float* b3  = (const float*)d_in[7];
    const float* w1b = (const float*)d_in[8];
    const float* g1b = (const float*)d_in[9];
    const float* b1b = (const float*)d_in[10];
    float* out = (float*)d_out;
    float* ws  = (float*)d_ws;

    const int n = in_sizes[0] / CIN;   // 150000

    // ws layout: stats[192] (pad 256 f32) | w1at | w3img | w1bt | t1 | ybuf | [zb]
    float* stats = ws;
    u16* w1at  = (u16*)(ws + 256);
    u16* w3img = w1at + 16384;
    u16* w1bt  = w3img + 110592;
    u16* t1    = w1bt + 16384;
    u16* ybuf  = t1 + (size_t)n * CB;
    u16* zb    = nullptr;
    {
        size_t need = 1024 + 286720 + (size_t)n * CB * 4 + (size_t)n * COUT * 2;
        if (ws_size >= need) zb = ybuf + (size_t)n * CB;
    }

    hipMemsetAsync(stats, 0, 192 * sizeof(float), stream);

    const int nb128 = (n + 127) / 128;
    const int nb256 = (n + 255) / 256;
    k_prep<<<560, 256, 0, stream>>>(w1a, w3, w1b, w1at, w3img, w1bt);
    k_gemm1<<<nb256, 256, 0, stream>>>(data, w1at, t1, stats, n);
    k_apply64<<<2048, 256, 0, stream>>>(t1, stats, g1a, b1a, n);
    k_conv<<<nb128, 256, 0, stream>>>(t1, neigh, w3img, ybuf, stats, n);
    k_gemm2<<<dim3(nb256, 4), 256, 0, stream>>>(ybuf, w1bt, out, zb, stats, g3, b3, n);
    if (zb)
        k_final_bf<<<2048, 256, 0, stream>>>(out, zb, data, stats + 128, g1b, b1b, n);
    else
        k_final<<<2048, 256, 0, stream>>>(out, data, stats + 128, g1b, b1b, n);
}